// Round 6
// baseline (537.007 us; speedup 1.0000x reference)
//
#include <hip/hip_runtime.h>

// ---------------------------------------------------------------------------
// casual MHA, MI355X. fp32 in/out, fp16 MFMA compute.
// q/k path uses 2-term fp16 split (hi+lo, 3 MFMA passes) to keep softmax
// logits (std ~1024) accurate enough that argmax-like softmax doesn't flip.
//
// R6: (a) activation split folded back INTO the pipelined proj_qk (A32
// staging + in-loop hi/lo cvt): R5's separate split_act was 128MB of extra
// HBM traffic (~35us); R2+R5 jointly showed the cvt VALU overlaps the MFMA
// pipe (2 waves/SIMD, matrix-pipe-bound k-step), so in-loop cvt is free in
// the 2-phase structure. (b) s_setprio(1) around flash MFMA clusters (T5,
// +4-7% on attn per guide m191; flash has 4 independent blocks/CU).
// R5: 2-phase dbuf pipeline in all GEMMs (stage k+1 BEFORE compute k, one
// barrier/k-step) -> all GEMMs now below flash in the top-5. Kept.
// R4: XCD-chunked swizzle (FETCH 414->88MB). Kept everywhere.
// R1: flash cross-tile prefetch regressed (+85MB FETCH, L2 reuse loss) ->
// flash keeps the serial tile body.
// ---------------------------------------------------------------------------

typedef __attribute__((ext_vector_type(8))) _Float16 half8;
typedef __attribute__((ext_vector_type(4))) float f32x4;

#define DEVI static __device__ __forceinline__

static constexpr int cB = 4, cS = 2048, cD = 1024, cH = 16, cDH = 64;
static constexpr int cM = cB * cS; // 8192

DEVI unsigned short h2b(_Float16 h) { union { _Float16 f; unsigned short u; } x; x.f = h; return x.u; }

DEVI void async16(const void* g, void* l) {
#if defined(__HIP_DEVICE_COMPILE__)
  __builtin_amdgcn_global_load_lds((const __attribute__((address_space(1))) unsigned int*)g,
                                   (__attribute__((address_space(3))) unsigned int*)l, 16, 0, 0);
#endif
}

// ---- fused weight splits: fp32 -> fp16 hi (+lo for Wq/Wk) -------------------
__global__ void split4_kernel(const float* __restrict__ Wq, const float* __restrict__ Wk,
                              const float* __restrict__ Wv, const float* __restrict__ Wo,
                              unsigned short* __restrict__ Wqh, unsigned short* __restrict__ Wql,
                              unsigned short* __restrict__ Wkh, unsigned short* __restrict__ Wkl,
                              unsigned short* __restrict__ Wvh, unsigned short* __restrict__ Woh) {
  const int w = blockIdx.x >> 10, blk = blockIdx.x & 1023;
  const float* in = (w == 0) ? Wq : (w == 1) ? Wk : (w == 2) ? Wv : Wo;
  unsigned short* hi = (w == 0) ? Wqh : (w == 1) ? Wkh : (w == 2) ? Wvh : Woh;
  unsigned short* lo = (w == 0) ? Wql : (w == 1) ? Wkl : nullptr;
  int i = (blk * 256 + (int)threadIdx.x) * 4;
  float4 v = *(const float4*)(in + i);
  _Float16 h0 = (_Float16)v.x, h1 = (_Float16)v.y, h2 = (_Float16)v.z, h3 = (_Float16)v.w;
  unsigned short th[4] = {h2b(h0), h2b(h1), h2b(h2), h2b(h3)};
  *(uint2*)(hi + i) = *(const uint2*)th;
  if (lo != nullptr) {
    unsigned short tl[4] = {h2b((_Float16)(v.x - (float)h0)), h2b((_Float16)(v.y - (float)h1)),
                            h2b((_Float16)(v.z - (float)h2)), h2b((_Float16)(v.w - (float)h3))};
    *(uint2*)(lo + i) = *(const uint2*)tl;
  }
}

// ---- Q/K projection: fp32 A (in-loop hi/lo cvt), 3-pass, 2-phase dbuf -------
// grid 1024 (= 8*128, XCD-chunked): wid [0,512) Q-proj, [512,1024) K-proj.
// LDS 64KB (A32 dbuf 32KB + Bh/Bl dbuf 32KB) -> 2 blocks/CU. k-step is
// matrix-pipe-bound (~1860 cyc/SIMD); cvt VALU (~380 cyc) overlaps free.
__global__ __launch_bounds__(256, 2) void proj_qk(
    const float* __restrict__ Qa, const float* __restrict__ Ka,
    const unsigned short* __restrict__ Wqh, const unsigned short* __restrict__ Wql,
    const unsigned short* __restrict__ Wkh, const unsigned short* __restrict__ Wkl,
    unsigned short* __restrict__ qph, unsigned short* __restrict__ qpl,
    unsigned short* __restrict__ kph, unsigned short* __restrict__ kpl) {
  constexpr int N = cD, K = cD;
  __shared__ float sA32[2][128 * 32];
  __shared__ unsigned short sBh[2][128 * 32];
  __shared__ unsigned short sBl[2][128 * 32];

  const int wid = ((int)blockIdx.x & 7) * 128 + ((int)blockIdx.x >> 3);
  const int job = wid >> 9; // 0=Q 1=K
  const int bid = wid & 511;
  const float* A32p = job ? Ka : Qa;
  const unsigned short* Bh = job ? Wkh : Wqh;
  const unsigned short* Bl = job ? Wkl : Wql;
  unsigned short* C0 = job ? kph : qph;
  unsigned short* C1 = job ? kpl : qpl;

  const int tid = threadIdx.x, lane = tid & 63, wave = tid >> 6;
  const int wm = wave >> 1, wn = wave & 1;
  const int bm = bid >> 3, bn = bid & 7;
  const long r0 = (long)bm * 128, c0 = (long)bn * 128;
  const int quad = lane >> 4, cl = lane & 15;
  const int lrow8 = lane >> 3, lg8 = lane & 7;
  const int lrow16 = lane >> 2, lg4 = lane & 3;

  f32x4 acc[4][4];
#pragma unroll
  for (int mt = 0; mt < 4; ++mt)
#pragma unroll
    for (int nt = 0; nt < 4; ++nt) acc[mt][nt] = f32x4{0.f, 0.f, 0.f, 0.f};

  auto stage = [&](int k0, int buf) {
#pragma unroll
    for (int c = 0; c < 4; ++c) {
      int cc = wave * 4 + c;
      int r = cc * 8 + lrow8;
      const float* g = A32p + (r0 + r) * (long)K + k0 + ((lg8 ^ lrow8) * 4);
      async16(g, &sA32[buf][cc * 256]);
    }
#pragma unroll
    for (int c = 0; c < 2; ++c) {
      int cc = wave * 2 + c;
      int r = cc * 16 + lrow16;
      long gb = (c0 + r) * (long)K + k0 + ((lg4 ^ ((lrow16 >> 1) & 3)) * 8);
      async16(Bh + gb, &sBh[buf][cc * 512]);
      async16(Bl + gb, &sBl[buf][cc * 512]);
    }
  };

  auto compute = [&](int buf) {
    half8 ah[4], al[4], bh8[4], bl8[4];
#pragma unroll
    for (int mt = 0; mt < 4; ++mt) {
      int r = wm * 64 + mt * 16 + cl;
      int s0 = (quad * 2 + 0) ^ (r & 7), s1 = (quad * 2 + 1) ^ (r & 7);
      float fa[8];
      *(float4*)(fa) = *(const float4*)(&sA32[buf][r * 32 + s0 * 4]);
      *(float4*)(fa + 4) = *(const float4*)(&sA32[buf][r * 32 + s1 * 4]);
#pragma unroll
      for (int j = 0; j < 8; ++j) {
        _Float16 hh = (_Float16)fa[j];
        ah[mt][j] = hh;
        al[mt][j] = (_Float16)(fa[j] - (float)hh);
      }
    }
#pragma unroll
    for (int nt = 0; nt < 4; ++nt) {
      int r = wn * 64 + nt * 16 + cl;
      int s = quad ^ ((r >> 1) & 3);
      bh8[nt] = *(const half8*)(&sBh[buf][r * 32 + s * 8]);
      bl8[nt] = *(const half8*)(&sBl[buf][r * 32 + s * 8]);
    }
#pragma unroll
    for (int mt = 0; mt < 4; ++mt)
#pragma unroll
      for (int nt = 0; nt < 4; ++nt) {
        acc[mt][nt] = __builtin_amdgcn_mfma_f32_16x16x32_f16(ah[mt], bh8[nt], acc[mt][nt], 0, 0, 0);
        acc[mt][nt] = __builtin_amdgcn_mfma_f32_16x16x32_f16(ah[mt], bl8[nt], acc[mt][nt], 0, 0, 0);
        acc[mt][nt] = __builtin_amdgcn_mfma_f32_16x16x32_f16(al[mt], bh8[nt], acc[mt][nt], 0, 0, 0);
      }
  };

  // 2-phase: stage(k+1) issued BEFORE compute(k); single barrier per k-step.
  stage(0, 0);
  __syncthreads();
  int cur = 0;
  for (int k0 = 32; k0 < K; k0 += 32) {
    stage(k0, cur ^ 1);
    compute(cur);
    __syncthreads();
    cur ^= 1;
  }
  compute(cur);

#pragma unroll
  for (int mt = 0; mt < 4; ++mt)
#pragma unroll
    for (int nt = 0; nt < 4; ++nt)
#pragma unroll
      for (int i = 0; i < 4; ++i) {
        long row = r0 + wm * 64 + mt * 16 + quad * 4 + i;
        long col = c0 + wn * 64 + nt * 16 + cl;
        float v = acc[mt][nt][i];
        _Float16 hh = (_Float16)v;
        C0[row * N + col] = h2b(hh);
        C1[row * N + col] = h2b((_Float16)(v - (float)hh));
      }
}

// ---- V projection: fp32 A, 1-pass, 2-phase dbuf pipeline --------------------
__global__ __launch_bounds__(256, 3) void proj_v(const float* __restrict__ Va,
                                                 const unsigned short* __restrict__ Wvh,
                                                 unsigned short* __restrict__ vp) {
  constexpr int N = cD, K = cD;
  __shared__ float sA32[2][128 * 32];         // 32KB
  __shared__ unsigned short sBh[2][128 * 32]; // 16KB

  const int wid = ((int)blockIdx.x & 7) * 64 + ((int)blockIdx.x >> 3); // 512=8*64
  const int bm = wid >> 3, bn = wid & 7;
  const long r0 = (long)bm * 128, c0 = (long)bn * 128;

  const int tid = threadIdx.x, lane = tid & 63, wave = tid >> 6;
  const int wm = wave >> 1, wn = wave & 1;
  const int quad = lane >> 4, cl = lane & 15;
  const int lrow8 = lane >> 3, lg8 = lane & 7;
  const int lrow16 = lane >> 2, lg4 = lane & 3;

  f32x4 acc[4][4];
#pragma unroll
  for (int mt = 0; mt < 4; ++mt)
#pragma unroll
    for (int nt = 0; nt < 4; ++nt) acc[mt][nt] = f32x4{0.f, 0.f, 0.f, 0.f};

  auto stage = [&](int k0, int buf) {
#pragma unroll
    for (int c = 0; c < 4; ++c) {
      int cc = wave * 4 + c;
      int r = cc * 8 + lrow8;
      const float* g = Va + (r0 + r) * (long)K + k0 + ((lg8 ^ lrow8) * 4);
      async16(g, &sA32[buf][cc * 256]);
    }
#pragma unroll
    for (int c = 0; c < 2; ++c) {
      int cc = wave * 2 + c;
      int r = cc * 16 + lrow16;
      long gb = (c0 + r) * (long)K + k0 + ((lg4 ^ ((lrow16 >> 1) & 3)) * 8);
      async16(Wvh + gb, &sBh[buf][cc * 512]);
    }
  };

  auto compute = [&](int buf) {
    half8 ah[4], bh8[4];
#pragma unroll
    for (int mt = 0; mt < 4; ++mt) {
      int r = wm * 64 + mt * 16 + cl;
      int s0 = (quad * 2 + 0) ^ (r & 7), s1 = (quad * 2 + 1) ^ (r & 7);
      float fa[8];
      *(float4*)(fa) = *(const float4*)(&sA32[buf][r * 32 + s0 * 4]);
      *(float4*)(fa + 4) = *(const float4*)(&sA32[buf][r * 32 + s1 * 4]);
#pragma unroll
      for (int j = 0; j < 8; ++j) ah[mt][j] = (_Float16)fa[j];
    }
#pragma unroll
    for (int nt = 0; nt < 4; ++nt) {
      int r = wn * 64 + nt * 16 + cl;
      int s = quad ^ ((r >> 1) & 3);
      bh8[nt] = *(const half8*)(&sBh[buf][r * 32 + s * 8]);
    }
#pragma unroll
    for (int mt = 0; mt < 4; ++mt)
#pragma unroll
      for (int nt = 0; nt < 4; ++nt)
        acc[mt][nt] = __builtin_amdgcn_mfma_f32_16x16x32_f16(ah[mt], bh8[nt], acc[mt][nt], 0, 0, 0);
  };

  stage(0, 0);
  __syncthreads();
  int cur = 0;
  for (int k0 = 32; k0 < K; k0 += 32) {
    stage(k0, cur ^ 1);
    compute(cur);
    __syncthreads();
    cur ^= 1;
  }
  compute(cur);

#pragma unroll
  for (int mt = 0; mt < 4; ++mt)
#pragma unroll
    for (int nt = 0; nt < 4; ++nt)
#pragma unroll
      for (int i = 0; i < 4; ++i) {
        long row = r0 + wm * 64 + mt * 16 + quad * 4 + i;
        long col = c0 + wn * 64 + nt * 16 + cl;
        vp[row * N + col] = h2b((_Float16)acc[mt][nt][i]);
      }
}

// ---- out-proj GEMM: f16 A @ B^T, fp32 out, 2-phase dbuf ---------------------
__global__ __launch_bounds__(256, 3) void gemm_out(const unsigned short* __restrict__ A16p,
                                                   const unsigned short* __restrict__ Bh,
                                                   float* __restrict__ C0, int M, int N, int K) {
  __shared__ unsigned short sA16[2][128 * 32];
  __shared__ unsigned short sB16[2][128 * 32];

  const int tid = threadIdx.x, lane = tid & 63, wave = tid >> 6;
  const int wm = wave >> 1, wn = wave & 1;
  const int nb = N >> 7;
  const int wid = ((int)blockIdx.x & 7) * 64 + ((int)blockIdx.x >> 3);
  const int bm = wid / nb, bn = wid % nb;
  const long r0 = (long)bm * 128, c0 = (long)bn * 128;
  const int quad = lane >> 4, cl = lane & 15;
  const int lrow16 = lane >> 2, lg4 = lane & 3;

  f32x4 acc[4][4];
#pragma unroll
  for (int mt = 0; mt < 4; ++mt)
#pragma unroll
    for (int nt = 0; nt < 4; ++nt) acc[mt][nt] = f32x4{0.f, 0.f, 0.f, 0.f};

  auto stage = [&](int k0, int buf) {
#pragma unroll
    for (int c = 0; c < 2; ++c) {
      int cc = wave * 2 + c;
      int r = cc * 16 + lrow16;
      int sw = (lg4 ^ ((lrow16 >> 1) & 3)) * 8;
      async16(A16p + (r0 + r) * (long)K + k0 + sw, &sA16[buf][cc * 512]);
      async16(Bh + (c0 + r) * (long)K + k0 + sw, &sB16[buf][cc * 512]);
    }
  };

  auto compute = [&](int buf) {
    half8 ah[4], bh8[4];
#pragma unroll
    for (int mt = 0; mt < 4; ++mt) {
      int r = wm * 64 + mt * 16 + cl;
      int s = quad ^ ((r >> 1) & 3);
      ah[mt] = *(const half8*)(&sA16[buf][r * 32 + s * 8]);
    }
#pragma unroll
    for (int nt = 0; nt < 4; ++nt) {
      int r = wn * 64 + nt * 16 + cl;
      int s = quad ^ ((r >> 1) & 3);
      bh8[nt] = *(const half8*)(&sB16[buf][r * 32 + s * 8]);
    }
#pragma unroll
    for (int mt = 0; mt < 4; ++mt)
#pragma unroll
      for (int nt = 0; nt < 4; ++nt)
        acc[mt][nt] = __builtin_amdgcn_mfma_f32_16x16x32_f16(ah[mt], bh8[nt], acc[mt][nt], 0, 0, 0);
  };

  stage(0, 0);
  __syncthreads();
  int cur = 0;
  for (int k0 = 32; k0 < K; k0 += 32) {
    stage(k0, cur ^ 1);
    compute(cur);
    __syncthreads();
    cur ^= 1;
  }
  compute(cur);

#pragma unroll
  for (int mt = 0; mt < 4; ++mt)
#pragma unroll
    for (int nt = 0; nt < 4; ++nt)
#pragma unroll
      for (int i = 0; i < 4; ++i) {
        long row = r0 + wm * 64 + mt * 16 + quad * 4 + i;
        long col = c0 + wn * 64 + nt * 16 + cl;
        C0[row * N + col] = acc[mt][nt][i];
      }
}

// ---- flash attention --------------------------------------------------------
// Verified 177us structure + T5 setprio around MFMA clusters. 1024 blocks;
// qt = 15 - (blockIdx>>6) -> heavy first; same-(b,h) blocks co-XCD.
// (256,3) -> 84 VGPR, no spill.
// NOTE (R1): cross-tile prefetch regressed (+85MB FETCH). Keep serial body.
__global__ __launch_bounds__(256, 3) void flash_kernel(
    const unsigned short* __restrict__ qh_g, const unsigned short* __restrict__ ql_g,
    const unsigned short* __restrict__ kh_g, const unsigned short* __restrict__ kl_g,
    const unsigned short* __restrict__ vp_g, unsigned short* __restrict__ out) {
  __shared__ unsigned short sKh[64 * 64];
  __shared__ unsigned short sKl[64 * 64];
  __shared__ unsigned int sVtU[64 * 34];    // V^T: [dh][k/2] dword-packed, stride 34
  __shared__ unsigned short sP[4][32 * 40]; // per-wave P chunk [32][40]

  const int tid = threadIdx.x, lane = tid & 63, wave = tid >> 6;
  const int quad = lane >> 4, cl = lane & 15;
  const int bh = blockIdx.x & 63;
  const int qt = 15 - (blockIdx.x >> 6);
  const int h = bh & 15;
  const int b = bh >> 4;
  const long rowbase = (long)b * cS;
  const int q0 = qt * 128;
  const int lrow8 = lane >> 3, lg8 = lane & 7;

  half8 qh[2][2], ql[2][2];
  const _Float16 s8 = (_Float16)0.125f;
#pragma unroll
  for (int ks = 0; ks < 2; ++ks)
#pragma unroll
    for (int mt = 0; mt < 2; ++mt) {
      long r = rowbase + q0 + wave * 32 + mt * 16 + cl;
      long off = r * cD + h * 64 + ks * 32 + quad * 8;
      qh[ks][mt] = *(const half8*)(qh_g + off) * s8;
      ql[ks][mt] = *(const half8*)(ql_g + off) * s8;
    }

  f32x4 O[2][5];
  float mrow[2][4];
#pragma unroll
  for (int mt = 0; mt < 2; ++mt) {
#pragma unroll
    for (int dt = 0; dt < 5; ++dt) O[mt][dt] = f32x4{0.f, 0.f, 0.f, 0.f};
#pragma unroll
    for (int i = 0; i < 4; ++i) mrow[mt][i] = -1e30f;
  }

  half8 vone;
#pragma unroll
  for (int j = 0; j < 8; ++j) vone[j] = (cl == 0) ? (_Float16)1.0f : (_Float16)0.0f;

  auto tile = [&](int ki, bool MASK) {
    __syncthreads();
#pragma unroll
    for (int c = 0; c < 2; ++c) {
      int cc = wave * 2 + c;
      int r = cc * 8 + lrow8;
      long g = (rowbase + ki * 64 + r) * (long)cD + h * 64 + ((lg8 ^ lrow8) * 8);
      async16(kh_g + g, sKh + cc * 512);
      async16(kl_g + g, sKl + cc * 512);
    }
    {
      int r2 = tid & 31, dc = (tid >> 5) * 8;
      const unsigned short* gv = vp_g + (rowbase + ki * 64 + 2 * r2) * (long)cD + h * 64 + dc;
      unsigned short a[8], bb[8];
      *(uint4*)a = *(const uint4*)gv;
      *(uint4*)bb = *(const uint4*)(gv + cD);
#pragma unroll
      for (int j = 0; j < 8; ++j)
        sVtU[(dc + j) * 34 + r2] = (unsigned int)a[j] | ((unsigned int)bb[j] << 16);
    }
    __syncthreads();

    f32x4 sacc[2][4];
#pragma unroll
    for (int mt = 0; mt < 2; ++mt)
#pragma unroll
      for (int nt = 0; nt < 4; ++nt) sacc[mt][nt] = f32x4{0.f, 0.f, 0.f, 0.f};
#pragma unroll
    for (int ks = 0; ks < 2; ++ks) {
      half8 kh8[4], kl8[4];
#pragma unroll
      for (int nt = 0; nt < 4; ++nt) {
        int r = nt * 16 + cl;
        int off = r * 64 + (((ks * 4 + quad) ^ (r & 7)) * 8);
        kh8[nt] = *(const half8*)(sKh + off);
        kl8[nt] = *(const half8*)(sKl + off);
      }
      __builtin_amdgcn_s_setprio(1);
#pragma unroll
      for (int mt = 0; mt < 2; ++mt)
#pragma unroll
        for (int nt = 0; nt < 4; ++nt) {
          sacc[mt][nt] = __builtin_amdgcn_mfma_f32_16x16x32_f16(qh[ks][mt], kh8[nt], sacc[mt][nt], 0, 0, 0);
          sacc[mt][nt] = __builtin_amdgcn_mfma_f32_16x16x32_f16(qh[ks][mt], kl8[nt], sacc[mt][nt], 0, 0, 0);
          sacc[mt][nt] = __builtin_amdgcn_mfma_f32_16x16x32_f16(ql[ks][mt], kh8[nt], sacc[mt][nt], 0, 0, 0);
        }
      __builtin_amdgcn_s_setprio(0);
    }
    if (MASK) {
#pragma unroll
      for (int mt = 0; mt < 2; ++mt)
#pragma unroll
        for (int nt = 0; nt < 4; ++nt)
#pragma unroll
          for (int i = 0; i < 4; ++i) {
            int rg = q0 + wave * 32 + mt * 16 + quad * 4 + i;
            int cg = ki * 64 + nt * 16 + cl;
            if (cg > rg) sacc[mt][nt][i] = -1e30f;
          }
    }
    float mnew[2][4];
    bool ch = false;
#pragma unroll
    for (int mt = 0; mt < 2; ++mt)
#pragma unroll
      for (int i = 0; i < 4; ++i) {
        float mx = fmaxf(fmaxf(sacc[mt][0][i], sacc[mt][1][i]),
                         fmaxf(sacc[mt][2][i], sacc[mt][3][i]));
#pragma unroll
        for (int d = 1; d < 16; d <<= 1) mx = fmaxf(mx, __shfl_xor(mx, d));
        ch |= (mx > mrow[mt][i]);
        mnew[mt][i] = fmaxf(mrow[mt][i], mx);
      }
    if (__ballot(ch)) {
#pragma unroll
      for (int mt = 0; mt < 2; ++mt)
#pragma unroll
        for (int i = 0; i < 4; ++i) {
          float a = __expf(mrow[mt][i] - mnew[mt][i]);
#pragma unroll
          for (int dt = 0; dt < 5; ++dt) O[mt][dt][i] *= a;
        }
    }
#pragma unroll
    for (int mt = 0; mt < 2; ++mt)
#pragma unroll
      for (int i = 0; i < 4; ++i) mrow[mt][i] = mnew[mt][i];

    unsigned short* sPw = sP[wave];
#pragma unroll
    for (int kc = 0; kc < 2; ++kc) {
#pragma unroll
      for (int mt = 0; mt < 2; ++mt)
#pragma unroll
        for (int ntl = 0; ntl < 2; ++ntl) {
          int nt = kc * 2 + ntl;
#pragma unroll
          for (int i = 0; i < 4; ++i) {
            float p = __expf(sacc[mt][nt][i] - mrow[mt][i]);
            sPw[(mt * 16 + quad * 4 + i) * 40 + ntl * 16 + cl] = h2b((_Float16)p);
          }
        }
      half8 pa[2], vb[4];
#pragma unroll
      for (int mt = 0; mt < 2; ++mt)
        pa[mt] = *(const half8*)(sPw + (mt * 16 + cl) * 40 + quad * 8);
#pragma unroll
      for (int dt = 0; dt < 4; ++dt) {
        int base = (dt * 16 + cl) * 34 + kc * 16 + quad * 4;
        union { uint4 u; half8 hh; } cvt;
        uint2 p0 = *(const uint2*)(sVtU + base);
        uint2 p1 = *(const uint2*)(sVtU + base + 2);
        cvt.u = uint4{p0.x, p0.y, p1.x, p1.y};
        vb[dt] = cvt.hh;
      }
      __builtin_amdgcn_s_setprio(1);
#pragma unroll
      for (int mt = 0; mt < 2; ++mt) {
#pragma unroll
        for (int dt = 0; dt < 4; ++dt)
          O[mt][dt] = __builtin_amdgcn_mfma_f32_16x16x32_f16(pa[mt], vb[dt], O[mt][dt], 0, 0, 0);
        O[mt][4] = __builtin_amdgcn_mfma_f32_16x16x32_f16(pa[mt], vone, O[mt][4], 0, 0, 0);
      }
      __builtin_amdgcn_s_setprio(0);
    }
  };

  const int full = 2 * qt;
  for (int ki = 0; ki < full; ++ki) tile(ki, false);
  tile(full, true);
  tile(full + 1, true);

  float lv[2][4];
#pragma unroll
  for (int mt = 0; mt < 2; ++mt)
#pragma unroll
    for (int i = 0; i < 4; ++i) lv[mt][i] = __shfl(O[mt][4][i], (lane & 48));
#pragma unroll
  for (int mt = 0; mt < 2; ++mt)
#pragma unroll
    for (int dt = 0; dt < 4; ++dt)
#pragma unroll
      for (int i = 0; i < 4; ++i) {
        long r = rowbase + q0 + wave * 32 + mt * 16 + quad * 4 + i;
        out[r * cD + h * 64 + dt * 16 + cl] = h2b((_Float16)(O[mt][dt][i] / lv[mt][i]));
      }
}

// ---------------------------------------------------------------------------
extern "C" void kernel_launch(void* const* d_in, const int* in_sizes, int n_in,
                              void* d_out, int out_size, void* d_ws, size_t ws_size,
                              hipStream_t stream) {
  const float* Q = (const float*)d_in[0];
  const float* K = (const float*)d_in[1];
  const float* V = (const float*)d_in[2];
  const float* Wq = (const float*)d_in[3];
  const float* Wk = (const float*)d_in[4];
  const float* Wv = (const float*)d_in[5];
  const float* Wo = (const float*)d_in[6];

  unsigned short* ws = (unsigned short*)d_ws;
  const size_t WD = (size_t)cD * cD;
  const size_t WM = (size_t)cM * cD;
  unsigned short* Wqh = ws;
  unsigned short* Wql = Wqh + WD;
  unsigned short* Wkh = Wql + WD;
  unsigned short* Wkl = Wkh + WD;
  unsigned short* Wvh = Wkl + WD;
  unsigned short* Woh = Wvh + WD;
  unsigned short* qph = Woh + WD;
  unsigned short* qpl = qph + WM;
  unsigned short* kph = qpl + WM;
  unsigned short* kpl = kph + WM;
  unsigned short* vp = kpl + WM;
  unsigned short* attnb = vp + WM;

  split4_kernel<<<4096, 256, 0, stream>>>(Wq, Wk, Wv, Wo, Wqh, Wql, Wkh, Wkl, Wvh, Woh);

  proj_qk<<<1024, 256, 0, stream>>>(Q, K, Wqh, Wql, Wkh, Wkl, qph, qpl, kph, kpl);
  proj_v<<<512, 256, 0, stream>>>(V, Wvh, vp);

  flash_kernel<<<cB * cH * 16, 256, 0, stream>>>(qph, qpl, kph, kpl, vp, attnb);

  const int gblk = (cM / 128) * (cD / 128); // 512
  gemm_out<<<gblk, 256, 0, stream>>>(attnb, Woh, (float*)d_out, cM, cD, cD);
}

// Round 8
// 487.562 us; speedup vs baseline: 1.1014x; 1.1014x over previous
//
#include <hip/hip_runtime.h>

// ---------------------------------------------------------------------------
// casual MHA, MI355X. fp32 in/out, fp16 MFMA compute.
// q/k path uses 2-term fp16 split (hi+lo, 3 MFMA passes) to keep softmax
// logits (std ~1024) accurate enough that argmax-like softmax doesn't flip.
//
// R8 = R7 resubmitted verbatim (R7 bench was an infra failure: "container
// failed twice"; no counters produced, theory unchanged).
//
// R7: occupancy-first GEMMs. Cross-round accounting: proj ran ~230us at BOTH
// 2-barrier/3blk (R0) and dbuf/2blk (R5) -> dbuf's pipeline gain exactly paid
// for its occupancy loss; R6's A32+dbuf (cvt at 2blk) was -50us worse. New
// config: f16 pre-split inputs, 32KB SINGLE-buffer LDS -> 4 blocks/CU
// (grid-bound), plain 2-barrier loop; TLP (16 waves/CU) hides the vmcnt
// drain like m97's 874TF structure. V-proj/gemm_out also lean single-buffer.
// Flash = exact verified 177us kernel (R6 setprio was -11us: barrier-locked
// waves, m190-style null -> removed).
// R4: XCD-chunked swizzle kept everywhere (FETCH 414->88MB, free).
// R1: no cross-tile prefetch in flash (+85MB FETCH = L2 KV thrash at 4blk/CU).
// ---------------------------------------------------------------------------

typedef __attribute__((ext_vector_type(8))) _Float16 half8;
typedef __attribute__((ext_vector_type(4))) float f32x4;

#define DEVI static __device__ __forceinline__

static constexpr int cB = 4, cS = 2048, cD = 1024, cH = 16, cDH = 64;
static constexpr int cM = cB * cS; // 8192

DEVI unsigned short h2b(_Float16 h) { union { _Float16 f; unsigned short u; } x; x.f = h; return x.u; }

DEVI void async16(const void* g, void* l) {
#if defined(__HIP_DEVICE_COMPILE__)
  __builtin_amdgcn_global_load_lds((const __attribute__((address_space(1))) unsigned int*)g,
                                   (__attribute__((address_space(3))) unsigned int*)l, 16, 0, 0);
#endif
}

// ---- fused weight splits: fp32 -> fp16 hi (+lo for Wq/Wk) -------------------
__global__ void split4_kernel(const float* __restrict__ Wq, const float* __restrict__ Wk,
                              const float* __restrict__ Wv, const float* __restrict__ Wo,
                              unsigned short* __restrict__ Wqh, unsigned short* __restrict__ Wql,
                              unsigned short* __restrict__ Wkh, unsigned short* __restrict__ Wkl,
                              unsigned short* __restrict__ Wvh, unsigned short* __restrict__ Woh) {
  const int w = blockIdx.x >> 10, blk = blockIdx.x & 1023;
  const float* in = (w == 0) ? Wq : (w == 1) ? Wk : (w == 2) ? Wv : Wo;
  unsigned short* hi = (w == 0) ? Wqh : (w == 1) ? Wkh : (w == 2) ? Wvh : Woh;
  unsigned short* lo = (w == 0) ? Wql : (w == 1) ? Wkl : nullptr;
  int i = (blk * 256 + (int)threadIdx.x) * 4;
  float4 v = *(const float4*)(in + i);
  _Float16 h0 = (_Float16)v.x, h1 = (_Float16)v.y, h2 = (_Float16)v.z, h3 = (_Float16)v.w;
  unsigned short th[4] = {h2b(h0), h2b(h1), h2b(h2), h2b(h3)};
  *(uint2*)(hi + i) = *(const uint2*)th;
  if (lo != nullptr) {
    unsigned short tl[4] = {h2b((_Float16)(v.x - (float)h0)), h2b((_Float16)(v.y - (float)h1)),
                            h2b((_Float16)(v.z - (float)h2)), h2b((_Float16)(v.w - (float)h3))};
    *(uint2*)(lo + i) = *(const uint2*)tl;
  }
}

// ---- activation splits: Q,K fp32 -> fp16 hi/lo ------------------------------
__global__ void split_act_kernel(const float* __restrict__ Q, const float* __restrict__ K,
                                 unsigned short* __restrict__ Qh, unsigned short* __restrict__ Ql,
                                 unsigned short* __restrict__ Kh, unsigned short* __restrict__ Kl) {
  const int t = blockIdx.x >> 13; // 8192 blocks per tensor
  const int blk = blockIdx.x & 8191;
  const float* in = t ? K : Q;
  unsigned short* hi = t ? Kh : Qh;
  unsigned short* lo = t ? Kl : Ql;
  int i = (blk * 256 + (int)threadIdx.x) * 4;
  float4 v = *(const float4*)(in + i);
  _Float16 h0 = (_Float16)v.x, h1 = (_Float16)v.y, h2 = (_Float16)v.z, h3 = (_Float16)v.w;
  unsigned short th[4] = {h2b(h0), h2b(h1), h2b(h2), h2b(h3)};
  *(uint2*)(hi + i) = *(const uint2*)th;
  unsigned short tl[4] = {h2b((_Float16)(v.x - (float)h0)), h2b((_Float16)(v.y - (float)h1)),
                          h2b((_Float16)(v.z - (float)h2)), h2b((_Float16)(v.w - (float)h3))};
  *(uint2*)(lo + i) = *(const uint2*)tl;
}

// ---- Q/K projection: f16 hi/lo inputs, 3-pass, 32KB single-buffer -----------
// grid 1024 (= 8*128, XCD-chunked): wid [0,512) Q-proj, [512,1024) K-proj.
// 32KB LDS -> 4 blocks/CU resident (grid-bound); 16 waves/CU of TLP hide the
// per-block barrier drain (m97 structure). 2-barrier loop; no dbuf.
__global__ __launch_bounds__(256, 3) void proj_qk(
    const unsigned short* __restrict__ Qh, const unsigned short* __restrict__ Ql,
    const unsigned short* __restrict__ Kh, const unsigned short* __restrict__ Kl,
    const unsigned short* __restrict__ Wqh, const unsigned short* __restrict__ Wql,
    const unsigned short* __restrict__ Wkh, const unsigned short* __restrict__ Wkl,
    unsigned short* __restrict__ qph, unsigned short* __restrict__ qpl,
    unsigned short* __restrict__ kph, unsigned short* __restrict__ kpl) {
  constexpr int N = cD, K = cD;
  __shared__ unsigned short sAh[128 * 32];
  __shared__ unsigned short sAl[128 * 32];
  __shared__ unsigned short sBh[128 * 32];
  __shared__ unsigned short sBl[128 * 32];

  const int wid = ((int)blockIdx.x & 7) * 128 + ((int)blockIdx.x >> 3);
  const int job = wid >> 9; // 0=Q 1=K
  const int bid = wid & 511;
  const unsigned short* Ah_g = job ? Kh : Qh;
  const unsigned short* Al_g = job ? Kl : Ql;
  const unsigned short* Bh = job ? Wkh : Wqh;
  const unsigned short* Bl = job ? Wkl : Wql;
  unsigned short* C0 = job ? kph : qph;
  unsigned short* C1 = job ? kpl : qpl;

  const int tid = threadIdx.x, lane = tid & 63, wave = tid >> 6;
  const int wm = wave >> 1, wn = wave & 1;
  const int bm = bid >> 3, bn = bid & 7;
  const long r0 = (long)bm * 128, c0 = (long)bn * 128;
  const int quad = lane >> 4, cl = lane & 15;
  const int lrow16 = lane >> 2, lg4 = lane & 3;

  f32x4 acc[4][4];
#pragma unroll
  for (int mt = 0; mt < 4; ++mt)
#pragma unroll
    for (int nt = 0; nt < 4; ++nt) acc[mt][nt] = f32x4{0.f, 0.f, 0.f, 0.f};

  for (int k0 = 0; k0 < K; k0 += 32) {
    __syncthreads();
#pragma unroll
    for (int c = 0; c < 2; ++c) {
      int cc = wave * 2 + c;
      int r = cc * 16 + lrow16;
      int sw = (lg4 ^ ((lrow16 >> 1) & 3)) * 8;
      long ga = (r0 + r) * (long)K + k0 + sw;
      long gb = (c0 + r) * (long)K + k0 + sw;
      async16(Ah_g + ga, sAh + cc * 512);
      async16(Al_g + ga, sAl + cc * 512);
      async16(Bh + gb, sBh + cc * 512);
      async16(Bl + gb, sBl + cc * 512);
    }
    __syncthreads();

    half8 ah[4], al[4], bh8[4], bl8[4];
#pragma unroll
    for (int mt = 0; mt < 4; ++mt) {
      int r = wm * 64 + mt * 16 + cl;
      int s = quad ^ ((r >> 1) & 3);
      ah[mt] = *(const half8*)(sAh + r * 32 + s * 8);
      al[mt] = *(const half8*)(sAl + r * 32 + s * 8);
    }
#pragma unroll
    for (int nt = 0; nt < 4; ++nt) {
      int r = wn * 64 + nt * 16 + cl;
      int s = quad ^ ((r >> 1) & 3);
      bh8[nt] = *(const half8*)(sBh + r * 32 + s * 8);
      bl8[nt] = *(const half8*)(sBl + r * 32 + s * 8);
    }
#pragma unroll
    for (int mt = 0; mt < 4; ++mt)
#pragma unroll
      for (int nt = 0; nt < 4; ++nt) {
        acc[mt][nt] = __builtin_amdgcn_mfma_f32_16x16x32_f16(ah[mt], bh8[nt], acc[mt][nt], 0, 0, 0);
        acc[mt][nt] = __builtin_amdgcn_mfma_f32_16x16x32_f16(ah[mt], bl8[nt], acc[mt][nt], 0, 0, 0);
        acc[mt][nt] = __builtin_amdgcn_mfma_f32_16x16x32_f16(al[mt], bh8[nt], acc[mt][nt], 0, 0, 0);
      }
  }

#pragma unroll
  for (int mt = 0; mt < 4; ++mt)
#pragma unroll
    for (int nt = 0; nt < 4; ++nt)
#pragma unroll
      for (int i = 0; i < 4; ++i) {
        long row = r0 + wm * 64 + mt * 16 + quad * 4 + i;
        long col = c0 + wn * 64 + nt * 16 + cl;
        float v = acc[mt][nt][i];
        _Float16 hh = (_Float16)v;
        C0[row * N + col] = h2b(hh);
        C1[row * N + col] = h2b((_Float16)(v - (float)hh));
      }
}

// ---- V projection: fp32 A, 1-pass, 24KB single-buffer -----------------------
__global__ __launch_bounds__(256, 3) void proj_v(const float* __restrict__ Va,
                                                 const unsigned short* __restrict__ Wvh,
                                                 unsigned short* __restrict__ vp) {
  constexpr int N = cD, K = cD;
  __shared__ float sA32[128 * 32];         // 16KB
  __shared__ unsigned short sBh[128 * 32]; // 8KB

  const int wid = ((int)blockIdx.x & 7) * 64 + ((int)blockIdx.x >> 3); // 512=8*64
  const int bm = wid >> 3, bn = wid & 7;
  const long r0 = (long)bm * 128, c0 = (long)bn * 128;

  const int tid = threadIdx.x, lane = tid & 63, wave = tid >> 6;
  const int wm = wave >> 1, wn = wave & 1;
  const int quad = lane >> 4, cl = lane & 15;
  const int lrow8 = lane >> 3, lg8 = lane & 7;
  const int lrow16 = lane >> 2, lg4 = lane & 3;

  f32x4 acc[4][4];
#pragma unroll
  for (int mt = 0; mt < 4; ++mt)
#pragma unroll
    for (int nt = 0; nt < 4; ++nt) acc[mt][nt] = f32x4{0.f, 0.f, 0.f, 0.f};

  for (int k0 = 0; k0 < K; k0 += 32) {
    __syncthreads();
#pragma unroll
    for (int c = 0; c < 4; ++c) {
      int cc = wave * 4 + c;
      int r = cc * 8 + lrow8;
      const float* g = Va + (r0 + r) * (long)K + k0 + ((lg8 ^ lrow8) * 4);
      async16(g, sA32 + cc * 256);
    }
#pragma unroll
    for (int c = 0; c < 2; ++c) {
      int cc = wave * 2 + c;
      int r = cc * 16 + lrow16;
      long gb = (c0 + r) * (long)K + k0 + ((lg4 ^ ((lrow16 >> 1) & 3)) * 8);
      async16(Wvh + gb, sBh + cc * 512);
    }
    __syncthreads();

    half8 ah[4], bh8[4];
#pragma unroll
    for (int mt = 0; mt < 4; ++mt) {
      int r = wm * 64 + mt * 16 + cl;
      int s0 = (quad * 2 + 0) ^ (r & 7), s1 = (quad * 2 + 1) ^ (r & 7);
      float fa[8];
      *(float4*)(fa) = *(const float4*)(sA32 + r * 32 + s0 * 4);
      *(float4*)(fa + 4) = *(const float4*)(sA32 + r * 32 + s1 * 4);
#pragma unroll
      for (int j = 0; j < 8; ++j) ah[mt][j] = (_Float16)fa[j];
    }
#pragma unroll
    for (int nt = 0; nt < 4; ++nt) {
      int r = wn * 64 + nt * 16 + cl;
      int s = quad ^ ((r >> 1) & 3);
      bh8[nt] = *(const half8*)(sBh + r * 32 + s * 8);
    }
#pragma unroll
    for (int mt = 0; mt < 4; ++mt)
#pragma unroll
      for (int nt = 0; nt < 4; ++nt)
        acc[mt][nt] = __builtin_amdgcn_mfma_f32_16x16x32_f16(ah[mt], bh8[nt], acc[mt][nt], 0, 0, 0);
  }

#pragma unroll
  for (int mt = 0; mt < 4; ++mt)
#pragma unroll
    for (int nt = 0; nt < 4; ++nt)
#pragma unroll
      for (int i = 0; i < 4; ++i) {
        long row = r0 + wm * 64 + mt * 16 + quad * 4 + i;
        long col = c0 + wn * 64 + nt * 16 + cl;
        vp[row * N + col] = h2b((_Float16)acc[mt][nt][i]);
      }
}

// ---- out-proj GEMM: f16 A @ B^T, fp32 out, 16KB single-buffer ---------------
__global__ __launch_bounds__(256, 2) void gemm_out(const unsigned short* __restrict__ A16p,
                                                   const unsigned short* __restrict__ Bh,
                                                   float* __restrict__ C0, int M, int N, int K) {
  __shared__ unsigned short sA16[128 * 32];
  __shared__ unsigned short sB16[128 * 32];

  const int tid = threadIdx.x, lane = tid & 63, wave = tid >> 6;
  const int wm = wave >> 1, wn = wave & 1;
  const int nb = N >> 7;
  const int wid = ((int)blockIdx.x & 7) * 64 + ((int)blockIdx.x >> 3);
  const int bm = wid / nb, bn = wid % nb;
  const long r0 = (long)bm * 128, c0 = (long)bn * 128;
  const int quad = lane >> 4, cl = lane & 15;
  const int lrow16 = lane >> 2, lg4 = lane & 3;

  f32x4 acc[4][4];
#pragma unroll
  for (int mt = 0; mt < 4; ++mt)
#pragma unroll
    for (int nt = 0; nt < 4; ++nt) acc[mt][nt] = f32x4{0.f, 0.f, 0.f, 0.f};

  for (int k0 = 0; k0 < K; k0 += 32) {
    __syncthreads();
#pragma unroll
    for (int c = 0; c < 2; ++c) {
      int cc = wave * 2 + c;
      int r = cc * 16 + lrow16;
      int sw = (lg4 ^ ((lrow16 >> 1) & 3)) * 8;
      async16(A16p + (r0 + r) * (long)K + k0 + sw, sA16 + cc * 512);
      async16(Bh + (c0 + r) * (long)K + k0 + sw, sB16 + cc * 512);
    }
    __syncthreads();

    half8 ah[4], bh8[4];
#pragma unroll
    for (int mt = 0; mt < 4; ++mt) {
      int r = wm * 64 + mt * 16 + cl;
      int s = quad ^ ((r >> 1) & 3);
      ah[mt] = *(const half8*)(sA16 + r * 32 + s * 8);
    }
#pragma unroll
    for (int nt = 0; nt < 4; ++nt) {
      int r = wn * 64 + nt * 16 + cl;
      int s = quad ^ ((r >> 1) & 3);
      bh8[nt] = *(const half8*)(sB16 + r * 32 + s * 8);
    }
#pragma unroll
    for (int mt = 0; mt < 4; ++mt)
#pragma unroll
      for (int nt = 0; nt < 4; ++nt)
        acc[mt][nt] = __builtin_amdgcn_mfma_f32_16x16x32_f16(ah[mt], bh8[nt], acc[mt][nt], 0, 0, 0);
  }

#pragma unroll
  for (int mt = 0; mt < 4; ++mt)
#pragma unroll
    for (int nt = 0; nt < 4; ++nt)
#pragma unroll
      for (int i = 0; i < 4; ++i) {
        long row = r0 + wm * 64 + mt * 16 + quad * 4 + i;
        long col = c0 + wn * 64 + nt * 16 + cl;
        C0[row * N + col] = acc[mt][nt][i];
      }
}

// ---- flash attention --------------------------------------------------------
// Exact verified 177us kernel. 1024 blocks; qt = 15 - (blockIdx>>6) -> heavy
// first; same-(b,h) blocks co-XCD. (256,3) -> 84 VGPR, no spill.
// NOTE (R1): cross-tile prefetch regressed (+85MB FETCH, L2 KV thrash).
// NOTE (R6): setprio around MFMA clusters was -11us (barrier-locked waves).
__global__ __launch_bounds__(256, 3) void flash_kernel(
    const unsigned short* __restrict__ qh_g, const unsigned short* __restrict__ ql_g,
    const unsigned short* __restrict__ kh_g, const unsigned short* __restrict__ kl_g,
    const unsigned short* __restrict__ vp_g, unsigned short* __restrict__ out) {
  __shared__ unsigned short sKh[64 * 64];
  __shared__ unsigned short sKl[64 * 64];
  __shared__ unsigned int sVtU[64 * 34];    // V^T: [dh][k/2] dword-packed, stride 34
  __shared__ unsigned short sP[4][32 * 40]; // per-wave P chunk [32][40]

  const int tid = threadIdx.x, lane = tid & 63, wave = tid >> 6;
  const int quad = lane >> 4, cl = lane & 15;
  const int bh = blockIdx.x & 63;
  const int qt = 15 - (blockIdx.x >> 6);
  const int h = bh & 15;
  const int b = bh >> 4;
  const long rowbase = (long)b * cS;
  const int q0 = qt * 128;
  const int lrow8 = lane >> 3, lg8 = lane & 7;

  half8 qh[2][2], ql[2][2];
  const _Float16 s8 = (_Float16)0.125f;
#pragma unroll
  for (int ks = 0; ks < 2; ++ks)
#pragma unroll
    for (int mt = 0; mt < 2; ++mt) {
      long r = rowbase + q0 + wave * 32 + mt * 16 + cl;
      long off = r * cD + h * 64 + ks * 32 + quad * 8;
      qh[ks][mt] = *(const half8*)(qh_g + off) * s8;
      ql[ks][mt] = *(const half8*)(ql_g + off) * s8;
    }

  f32x4 O[2][5];
  float mrow[2][4];
#pragma unroll
  for (int mt = 0; mt < 2; ++mt) {
#pragma unroll
    for (int dt = 0; dt < 5; ++dt) O[mt][dt] = f32x4{0.f, 0.f, 0.f, 0.f};
#pragma unroll
    for (int i = 0; i < 4; ++i) mrow[mt][i] = -1e30f;
  }

  half8 vone;
#pragma unroll
  for (int j = 0; j < 8; ++j) vone[j] = (cl == 0) ? (_Float16)1.0f : (_Float16)0.0f;

  auto tile = [&](int ki, bool MASK) {
    __syncthreads();
#pragma unroll
    for (int c = 0; c < 2; ++c) {
      int cc = wave * 2 + c;
      int r = cc * 8 + lrow8;
      long g = (rowbase + ki * 64 + r) * (long)cD + h * 64 + ((lg8 ^ lrow8) * 8);
      async16(kh_g + g, sKh + cc * 512);
      async16(kl_g + g, sKl + cc * 512);
    }
    {
      int r2 = tid & 31, dc = (tid >> 5) * 8;
      const unsigned short* gv = vp_g + (rowbase + ki * 64 + 2 * r2) * (long)cD + h * 64 + dc;
      unsigned short a[8], bb[8];
      *(uint4*)a = *(const uint4*)gv;
      *(uint4*)bb = *(const uint4*)(gv + cD);
#pragma unroll
      for (int j = 0; j < 8; ++j)
        sVtU[(dc + j) * 34 + r2] = (unsigned int)a[j] | ((unsigned int)bb[j] << 16);
    }
    __syncthreads();

    f32x4 sacc[2][4];
#pragma unroll
    for (int mt = 0; mt < 2; ++mt)
#pragma unroll
      for (int nt = 0; nt < 4; ++nt) sacc[mt][nt] = f32x4{0.f, 0.f, 0.f, 0.f};
#pragma unroll
    for (int ks = 0; ks < 2; ++ks) {
      half8 kh8[4], kl8[4];
#pragma unroll
      for (int nt = 0; nt < 4; ++nt) {
        int r = nt * 16 + cl;
        int off = r * 64 + (((ks * 4 + quad) ^ (r & 7)) * 8);
        kh8[nt] = *(const half8*)(sKh + off);
        kl8[nt] = *(const half8*)(sKl + off);
      }
#pragma unroll
      for (int mt = 0; mt < 2; ++mt)
#pragma unroll
        for (int nt = 0; nt < 4; ++nt) {
          sacc[mt][nt] = __builtin_amdgcn_mfma_f32_16x16x32_f16(qh[ks][mt], kh8[nt], sacc[mt][nt], 0, 0, 0);
          sacc[mt][nt] = __builtin_amdgcn_mfma_f32_16x16x32_f16(qh[ks][mt], kl8[nt], sacc[mt][nt], 0, 0, 0);
          sacc[mt][nt] = __builtin_amdgcn_mfma_f32_16x16x32_f16(ql[ks][mt], kh8[nt], sacc[mt][nt], 0, 0, 0);
        }
    }
    if (MASK) {
#pragma unroll
      for (int mt = 0; mt < 2; ++mt)
#pragma unroll
        for (int nt = 0; nt < 4; ++nt)
#pragma unroll
          for (int i = 0; i < 4; ++i) {
            int rg = q0 + wave * 32 + mt * 16 + quad * 4 + i;
            int cg = ki * 64 + nt * 16 + cl;
            if (cg > rg) sacc[mt][nt][i] = -1e30f;
          }
    }
    float mnew[2][4];
    bool ch = false;
#pragma unroll
    for (int mt = 0; mt < 2; ++mt)
#pragma unroll
      for (int i = 0; i < 4; ++i) {
        float mx = fmaxf(fmaxf(sacc[mt][0][i], sacc[mt][1][i]),
                         fmaxf(sacc[mt][2][i], sacc[mt][3][i]));
#pragma unroll
        for (int d = 1; d < 16; d <<= 1) mx = fmaxf(mx, __shfl_xor(mx, d));
        ch |= (mx > mrow[mt][i]);
        mnew[mt][i] = fmaxf(mrow[mt][i], mx);
      }
    if (__ballot(ch)) {
#pragma unroll
      for (int mt = 0; mt < 2; ++mt)
#pragma unroll
        for (int i = 0; i < 4; ++i) {
          float a = __expf(mrow[mt][i] - mnew[mt][i]);
#pragma unroll
          for (int dt = 0; dt < 5; ++dt) O[mt][dt][i] *= a;
        }
    }
#pragma unroll
    for (int mt = 0; mt < 2; ++mt)
#pragma unroll
      for (int i = 0; i < 4; ++i) mrow[mt][i] = mnew[mt][i];

    unsigned short* sPw = sP[wave];
#pragma unroll
    for (int kc = 0; kc < 2; ++kc) {
#pragma unroll
      for (int mt = 0; mt < 2; ++mt)
#pragma unroll
        for (int ntl = 0; ntl < 2; ++ntl) {
          int nt = kc * 2 + ntl;
#pragma unroll
          for (int i = 0; i < 4; ++i) {
            float p = __expf(sacc[mt][nt][i] - mrow[mt][i]);
            sPw[(mt * 16 + quad * 4 + i) * 40 + ntl * 16 + cl] = h2b((_Float16)p);
          }
        }
      half8 pa[2], vb[4];
#pragma unroll
      for (int mt = 0; mt < 2; ++mt)
        pa[mt] = *(const half8*)(sPw + (mt * 16 + cl) * 40 + quad * 8);
#pragma unroll
      for (int dt = 0; dt < 4; ++dt) {
        int base = (dt * 16 + cl) * 34 + kc * 16 + quad * 4;
        union { uint4 u; half8 hh; } cvt;
        uint2 p0 = *(const uint2*)(sVtU + base);
        uint2 p1 = *(const uint2*)(sVtU + base + 2);
        cvt.u = uint4{p0.x, p0.y, p1.x, p1.y};
        vb[dt] = cvt.hh;
      }
#pragma unroll
      for (int mt = 0; mt < 2; ++mt) {
#pragma unroll
        for (int dt = 0; dt < 4; ++dt)
          O[mt][dt] = __builtin_amdgcn_mfma_f32_16x16x32_f16(pa[mt], vb[dt], O[mt][dt], 0, 0, 0);
        O[mt][4] = __builtin_amdgcn_mfma_f32_16x16x32_f16(pa[mt], vone, O[mt][4], 0, 0, 0);
      }
    }
  };

  const int full = 2 * qt;
  for (int ki = 0; ki < full; ++ki) tile(ki, false);
  tile(full, true);
  tile(full + 1, true);

  float lv[2][4];
#pragma unroll
  for (int mt = 0; mt < 2; ++mt)
#pragma unroll
    for (int i = 0; i < 4; ++i) lv[mt][i] = __shfl(O[mt][4][i], (lane & 48));
#pragma unroll
  for (int mt = 0; mt < 2; ++mt)
#pragma unroll
    for (int dt = 0; dt < 4; ++dt)
#pragma unroll
      for (int i = 0; i < 4; ++i) {
        long r = rowbase + q0 + wave * 32 + mt * 16 + quad * 4 + i;
        out[r * cD + h * 64 + dt * 16 + cl] = h2b((_Float16)(O[mt][dt][i] / lv[mt][i]));
      }
}

// ---------------------------------------------------------------------------
extern "C" void kernel_launch(void* const* d_in, const int* in_sizes, int n_in,
                              void* d_out, int out_size, void* d_ws, size_t ws_size,
                              hipStream_t stream) {
  const float* Q = (const float*)d_in[0];
  const float* K = (const float*)d_in[1];
  const float* V = (const float*)d_in[2];
  const float* Wq = (const float*)d_in[3];
  const float* Wk = (const float*)d_in[4];
  const float* Wv = (const float*)d_in[5];
  const float* Wo = (const float*)d_in[6];

  unsigned short* ws = (unsigned short*)d_ws;
  const size_t WD = (size_t)cD * cD;
  const size_t WM = (size_t)cM * cD;
  // weights (6 WD)
  unsigned short* Wqh = ws;
  unsigned short* Wql = Wqh + WD;
  unsigned short* Wkh = Wql + WD;
  unsigned short* Wkl = Wkh + WD;
  unsigned short* Wvh = Wkl + WD;
  unsigned short* Woh = Wvh + WD;
  // 6 WM regions in ws; Qh/Ql live in d_out (32MB = 2 WM, dead before the
  // final gemm_out writes d_out).
  unsigned short* R1 = Woh + WD; // Kh  -> later vp (proj_v runs after proj_qk)
  unsigned short* R2 = R1 + WM;  // Kl  -> later attnb (flash runs after proj_qk)
  unsigned short* qph = R2 + WM;
  unsigned short* qpl = qph + WM;
  unsigned short* kph = qpl + WM;
  unsigned short* kpl = kph + WM;

  unsigned short* Qh = (unsigned short*)d_out;
  unsigned short* Ql = Qh + WM;
  unsigned short* Kh = R1;
  unsigned short* Kl = R2;
  unsigned short* vp = R1;
  unsigned short* attnb = R2;

  split4_kernel<<<4096, 256, 0, stream>>>(Wq, Wk, Wv, Wo, Wqh, Wql, Wkh, Wkl, Wvh, Woh);
  split_act_kernel<<<16384, 256, 0, stream>>>(Q, K, Qh, Ql, Kh, Kl);

  proj_qk<<<1024, 256, 0, stream>>>(Qh, Ql, Kh, Kl, Wqh, Wql, Wkh, Wkl,
                                    qph, qpl, kph, kpl);
  proj_v<<<512, 256, 0, stream>>>(V, Wvh, vp); // overwrites Kh (dead)

  flash_kernel<<<cB * cH * 16, 256, 0, stream>>>(qph, qpl, kph, kpl, vp, attnb);

  const int gblk = (cM / 128) * (cD / 128); // 512
  gemm_out<<<gblk, 256, 0, stream>>>(attnb, Woh, (float*)d_out, cM, cD, cD);
}